// Round 1
// baseline (949.094 us; speedup 1.0000x reference)
//
#include <hip/hip_runtime.h>

// SwinV2 block, MI355X. All heavy matmuls in bf16 MFMA (16x16x32), fp32 accum.
// Scratch layout (needs ~401 MB of d_ws):
//   region A @0        : qkv bf16 (170MB) -> proj_out bf16 (57MB) -> h bf16 (227MB)
//   region B @226.5MB  : attn_out bf16 (56.6MB) -> t2 bf16 (56.6MB)
//   y1 fp32 @283.1MB   : 113.2MB
//   bias16 fp32, cpb tab, transposed bf16 weights, fused qkv bias

typedef unsigned int uint32;
typedef unsigned short u16;
typedef __attribute__((ext_vector_type(4))) float f32x4;
typedef __attribute__((ext_vector_type(8))) __bf16 bf16x8;

#define M_TOK 73728   // 512 windows * 144 tokens = 32 * 2304 pixels

static __device__ __forceinline__ u16 f2bf(float f) {
    union { float f; uint32 u; } v; v.f = f;
    uint32 r = v.u + 0x7fffu + ((v.u >> 16) & 1u);
    return (u16)(r >> 16);
}
static __device__ __forceinline__ float bf2f(u16 h) {
    union { uint32 u; float f; } v; v.u = ((uint32)h) << 16; return v.f;
}
static __device__ __forceinline__ uint32 pack2(float a, float b) {
    return (uint32)f2bf(a) | ((uint32)f2bf(b) << 16);
}
static __device__ __forceinline__ float blo(uint32 u){ union{uint32 u;float f;}v; v.u=u<<16; return v.f; }
static __device__ __forceinline__ float bhi(uint32 u){ union{uint32 u;float f;}v; v.u=u&0xffff0000u; return v.f; }

// ---------------- setup kernels ----------------

// WT[n][k] = bf16(W[k][n]); W is (K,N) row-major fp32
__global__ void wt_convert(const float* __restrict__ W, u16* __restrict__ WT, int K, int N) {
    long idx = (long)blockIdx.x * 256 + threadIdx.x;
    long tot = (long)K * N;
    if (idx >= tot) return;
    int n = (int)(idx / K), k = (int)(idx - (long)n * K);
    WT[idx] = f2bf(W[(long)k * N + n]);
}

__global__ void build_qkv_bias(const float* __restrict__ qb, const float* __restrict__ vb,
                               float* __restrict__ outb) {
    int c = blockIdx.x * 256 + threadIdx.x;
    if (c >= 1152) return;
    outb[c] = (c < 384) ? qb[c] : ((c < 768) ? 0.f : vb[c - 768]);
}

// tab[e][h] = (relu(table[e] @ w1 + b1) @ w2)[h]   e in [0,529)
__global__ void cpb_tab(const float* __restrict__ table, const float* __restrict__ w1,
                        const float* __restrict__ b1, const float* __restrict__ w2,
                        float* __restrict__ tab) {
    __shared__ float hid[512];
    int e = blockIdx.x;
    float tx = table[e * 2 + 0], ty = table[e * 2 + 1];
    for (int u = threadIdx.x; u < 512; u += 256)
        hid[u] = fmaxf(tx * w1[u] + ty * w1[512 + u] + b1[u], 0.f);
    __syncthreads();
    if (threadIdx.x < 12) {
        float s = 0.f;
        for (int u = 0; u < 512; ++u) s += hid[u] * w2[u * 12 + threadIdx.x];
        tab[e * 12 + threadIdx.x] = s;
    }
}

// bias16[h][i][j] = 16*sigmoid(tab[rpi[i*144+j]][h])
__global__ void cpb_bias(const float* __restrict__ tab, const int* __restrict__ rpi,
                         float* __restrict__ bias16) {
    int idx = blockIdx.x * 256 + threadIdx.x;
    if (idx >= 12 * 144 * 144) return;
    int h = idx / 20736, ij = idx - h * 20736;
    float t = tab[rpi[ij] * 12 + h];
    bias16[idx] = 16.f / (1.f + __expf(-t));
}

// ---------------- GEMM (128x128 tile, BK=32, 4 waves, reg-staged) ----------------

enum { EPI_QKV = 0, EPI_PLAIN = 1, EPI_GELU = 2 };

template<bool A_F32, bool GATHER, int EPI>
__global__ __launch_bounds__(256) void gemm_k(
    const void* __restrict__ Ap, const u16* __restrict__ BT,
    const float* __restrict__ bias, u16* __restrict__ outp,
    int N, int K)
{
    __shared__ __align__(16) u16 As[128][40];
    __shared__ __align__(16) u16 Bs[128][40];
    const int tid = threadIdx.x;
    const int lane = tid & 63, wid = tid >> 6;
    const int wrow = (wid >> 1) << 6, wcol = (wid & 1) << 6;
    const int m0 = blockIdx.x << 7, n0 = blockIdx.y << 7;
    const int srow = tid >> 1, soff = (tid & 1) << 4;

    long a_off;
    {
        int arow = m0 + srow;
        if (GATHER) {
            // window token -> shifted-source pixel row of x
            int win = arow / 144, n = arow - win * 144;
            int b = win >> 4, wi = win & 15;
            int r = n / 12, cc = n - r * 12;
            int sh = ((wi >> 2) * 12 + r + 6) % 48;
            int sw = ((wi & 3) * 12 + cc + 6) % 48;
            a_off = ((long)(b * 2304 + sh * 48 + sw)) * K;
        } else {
            a_off = (long)arow * K;
        }
    }
    const long b_off = (long)(n0 + srow) * K;

    f32x4 acc[4][4];
    const f32x4 zero4 = {0.f, 0.f, 0.f, 0.f};
#pragma unroll
    for (int i = 0; i < 4; ++i)
#pragma unroll
        for (int j = 0; j < 4; ++j) acc[i][j] = zero4;

    float4 fa0, fa1, fa2, fa3;
    uint4 ua0, ua1, ub0, ub1;

    auto loadAB = [&](int k0) {
        if constexpr (A_F32) {
            const float4* A = (const float4*)((const float*)Ap + a_off + k0 + soff);
            fa0 = A[0]; fa1 = A[1]; fa2 = A[2]; fa3 = A[3];
        } else {
            const uint4* A = (const uint4*)((const u16*)Ap + a_off + k0 + soff);
            ua0 = A[0]; ua1 = A[1];
        }
        const uint4* Bp = (const uint4*)(BT + b_off + k0 + soff);
        ub0 = Bp[0]; ub1 = Bp[1];
    };
    auto storeLDS = [&]() {
        if constexpr (A_F32) {
            uint4 w0, w1;
            w0.x = pack2(fa0.x, fa0.y); w0.y = pack2(fa0.z, fa0.w);
            w0.z = pack2(fa1.x, fa1.y); w0.w = pack2(fa1.z, fa1.w);
            w1.x = pack2(fa2.x, fa2.y); w1.y = pack2(fa2.z, fa2.w);
            w1.z = pack2(fa3.x, fa3.y); w1.w = pack2(fa3.z, fa3.w);
            *(uint4*)&As[srow][soff] = w0;
            *(uint4*)&As[srow][soff + 8] = w1;
        } else {
            *(uint4*)&As[srow][soff] = ua0;
            *(uint4*)&As[srow][soff + 8] = ua1;
        }
        *(uint4*)&Bs[srow][soff] = ub0;
        *(uint4*)&Bs[srow][soff + 8] = ub1;
    };

    const int fr = lane & 15, fk = (lane >> 4) << 3;
    const int nk = K >> 5;
    loadAB(0);
    for (int kt = 0; kt < nk; ++kt) {
        __syncthreads();
        storeLDS();
        __syncthreads();
        if (kt + 1 < nk) loadAB((kt + 1) << 5);  // overlap next-tile loads with MFMA
        bf16x8 af[4], bg[4];
#pragma unroll
        for (int i = 0; i < 4; ++i) af[i] = *(const bf16x8*)&As[wrow + i * 16 + fr][fk];
#pragma unroll
        for (int j = 0; j < 4; ++j) bg[j] = *(const bf16x8*)&Bs[wcol + j * 16 + fr][fk];
#pragma unroll
        for (int i = 0; i < 4; ++i)
#pragma unroll
            for (int j = 0; j < 4; ++j)
                acc[i][j] = __builtin_amdgcn_mfma_f32_16x16x32_bf16(af[i], bg[j], acc[i][j], 0, 0, 0);
    }

    const int rbase = (lane >> 4) << 2;
#pragma unroll
    for (int i = 0; i < 4; ++i) {
#pragma unroll
        for (int j = 0; j < 4; ++j) {
            const int gn = n0 + wcol + j * 16 + fr;
            const float bv = bias[gn];
#pragma unroll
            for (int r = 0; r < 4; ++r) {
                const int gm = m0 + wrow + i * 16 + rbase + r;
                float v = acc[i][j][r] + bv;
                if constexpr (EPI == EPI_GELU)
                    v = 0.5f * v * (1.f + erff(v * 0.70710678118654752f));
                if constexpr (EPI == EPI_QKV) {
                    int win = gm / 144, n = gm - win * 144;
                    int which = gn / 384, c = gn - which * 384;
                    int head = c >> 5, d = c & 31;
                    outp[(((long)win * 3 + which) * 12 + head) * 4608 + n * 32 + d] = f2bf(v);
                } else {
                    outp[(long)gm * N + gn] = f2bf(v);
                }
            }
        }
    }
}

// ---------------- attention: one (window, head) per block, 3 waves ----------------

__global__ __launch_bounds__(192) void attn_k(
    const u16* __restrict__ qkv,      // [512][3][12][144][32] bf16
    const float* __restrict__ bias16, // [12][144][144]
    const float* __restrict__ mask,   // [16][144][144]
    const float* __restrict__ lsc,    // [12]
    u16* __restrict__ attn_o)         // [512][144][384] bf16
{
    __shared__ __align__(16) u16 KL[144][40];     // normalized K, row-major
    __shared__ __align__(16) u16 VT[32][168];     // V transposed [d][n], n padded to 160 (zeros)
    __shared__ __align__(16) u16 PL[3][16][168];  // per-wave P strip, cols padded to 160 (zeros)
    const int blk = blockIdx.x;
    const int win = blk / 12, head = blk - win * 12;
    const int tid = threadIdx.x, lane = tid & 63, wid = tid >> 6;
    const long base = ((long)win * 36 + head) * 4608;
    const u16* Qp = qkv + base;
    const u16* Kp = qkv + base + 12 * 4608;
    const u16* Vp = qkv + base + 24 * 4608;
    const float scale = __expf(fminf(lsc[head], 4.6051701859880914f)); // ln(100)

    if (tid < 144) {
        // K row: normalize, store
        const uint4* s = (const uint4*)(Kp + tid * 32);
        uint4 uu[4] = { s[0], s[1], s[2], s[3] };
        float f[32];
#pragma unroll
        for (int q = 0; q < 4; ++q) {
            f[q*8+0]=blo(uu[q].x); f[q*8+1]=bhi(uu[q].x);
            f[q*8+2]=blo(uu[q].y); f[q*8+3]=bhi(uu[q].y);
            f[q*8+4]=blo(uu[q].z); f[q*8+5]=bhi(uu[q].z);
            f[q*8+6]=blo(uu[q].w); f[q*8+7]=bhi(uu[q].w);
        }
        float ss = 0.f;
#pragma unroll
        for (int i = 0; i < 32; ++i) ss += f[i] * f[i];
        float inv = 1.f / fmaxf(sqrtf(ss), 1e-12f);
        uint32 pk[16];
#pragma unroll
        for (int i = 0; i < 16; ++i) pk[i] = pack2(f[2*i] * inv, f[2*i+1] * inv);
        uint4* d = (uint4*)&KL[tid][0];
        d[0] = make_uint4(pk[0], pk[1], pk[2], pk[3]);
        d[1] = make_uint4(pk[4], pk[5], pk[6], pk[7]);
        d[2] = make_uint4(pk[8], pk[9], pk[10], pk[11]);
        d[3] = make_uint4(pk[12], pk[13], pk[14], pk[15]);
        // V row -> transposed store
        const uint4* sv = (const uint4*)(Vp + tid * 32);
        uint4 vv[4] = { sv[0], sv[1], sv[2], sv[3] };
        u16 vs[32];
#pragma unroll
        for (int q = 0; q < 4; ++q) {
            vs[q*8+0] = (u16)(vv[q].x & 0xffffu); vs[q*8+1] = (u16)(vv[q].x >> 16);
            vs[q*8+2] = (u16)(vv[q].y & 0xffffu); vs[q*8+3] = (u16)(vv[q].y >> 16);
            vs[q*8+4] = (u16)(vv[q].z & 0xffffu); vs[q*8+5] = (u16)(vv[q].z >> 16);
            vs[q*8+6] = (u16)(vv[q].w & 0xffffu); vs[q*8+7] = (u16)(vv[q].w >> 16);
        }
#pragma unroll
        for (int d2 = 0; d2 < 32; ++d2) VT[d2][tid] = vs[d2];
    }
    for (int idx = tid; idx < 512; idx += 192) VT[idx >> 4][144 + (idx & 15)] = 0;
    __syncthreads();

    const int fr = lane & 15, fk = (lane >> 4) << 3, rb = (lane >> 4) << 2;
    const int wim = win & 15;
    const f32x4 zero4 = {0.f, 0.f, 0.f, 0.f};

    for (int s = wid; s < 9; s += 3) {
        // Q fragment (A layout), normalized * scale
        const uint4 qu = *(const uint4*)(Qp + (s * 16 + fr) * 32 + fk);
        float qf[8];
        qf[0]=blo(qu.x); qf[1]=bhi(qu.x); qf[2]=blo(qu.y); qf[3]=bhi(qu.y);
        qf[4]=blo(qu.z); qf[5]=bhi(qu.z); qf[6]=blo(qu.w); qf[7]=bhi(qu.w);
        float ss = 0.f;
#pragma unroll
        for (int i = 0; i < 8; ++i) ss += qf[i] * qf[i];
        ss += __shfl_xor(ss, 16);
        ss += __shfl_xor(ss, 32);
        float qinv = scale / fmaxf(sqrtf(ss), 1e-12f);
        union { uint32 u[4]; bf16x8 v; } cv;
#pragma unroll
        for (int i = 0; i < 4; ++i) cv.u[i] = pack2(qf[2*i] * qinv, qf[2*i+1] * qinv);
        bf16x8 aq = cv.v;

        f32x4 sacc[9];
#pragma unroll
        for (int jt = 0; jt < 9; ++jt) sacc[jt] = zero4;
#pragma unroll
        for (int jt = 0; jt < 9; ++jt) {
            bf16x8 bk = *(const bf16x8*)&KL[jt * 16 + fr][fk];
            sacc[jt] = __builtin_amdgcn_mfma_f32_16x16x32_bf16(aq, bk, sacc[jt], 0, 0, 0);
        }
        // + relative-position bias + shifted-window mask ; rowwise softmax
        float mx[4] = {-1e30f, -1e30f, -1e30f, -1e30f};
#pragma unroll
        for (int jt = 0; jt < 9; ++jt) {
            int gj = jt * 16 + fr;
#pragma unroll
            for (int r = 0; r < 4; ++r) {
                int gi = s * 16 + rb + r;
                float v = sacc[jt][r] + bias16[(head * 144 + gi) * 144 + gj]
                                      + mask[(wim * 144 + gi) * 144 + gj];
                sacc[jt][r] = v;
                mx[r] = fmaxf(mx[r], v);
            }
        }
#pragma unroll
        for (int r = 0; r < 4; ++r) {
#pragma unroll
            for (int o = 1; o < 16; o <<= 1) mx[r] = fmaxf(mx[r], __shfl_xor(mx[r], o));
        }
        float sm[4] = {0.f, 0.f, 0.f, 0.f};
#pragma unroll
        for (int jt = 0; jt < 9; ++jt)
#pragma unroll
            for (int r = 0; r < 4; ++r) {
                float e = __expf(sacc[jt][r] - mx[r]);
                sacc[jt][r] = e;
                sm[r] += e;
            }
#pragma unroll
        for (int r = 0; r < 4; ++r) {
#pragma unroll
            for (int o = 1; o < 16; o <<= 1) sm[r] += __shfl_xor(sm[r], o);
            sm[r] = 1.f / sm[r];
        }
        // stage unnormalized P (<=1) ; normalize at output store
#pragma unroll
        for (int jt = 0; jt < 9; ++jt)
#pragma unroll
            for (int r = 0; r < 4; ++r)
                PL[wid][rb + r][jt * 16 + fr] = f2bf(sacc[jt][r]);
#pragma unroll
        for (int r = 0; r < 4; ++r) PL[wid][rb + r][144 + fr] = 0;

        f32x4 oa0 = zero4, oa1 = zero4;
#pragma unroll
        for (int kt = 0; kt < 5; ++kt) {
            bf16x8 ap  = *(const bf16x8*)&PL[wid][fr][kt * 32 + fk];
            bf16x8 bv0 = *(const bf16x8*)&VT[fr][kt * 32 + fk];
            bf16x8 bv1 = *(const bf16x8*)&VT[16 + fr][kt * 32 + fk];
            oa0 = __builtin_amdgcn_mfma_f32_16x16x32_bf16(ap, bv0, oa0, 0, 0, 0);
            oa1 = __builtin_amdgcn_mfma_f32_16x16x32_bf16(ap, bv1, oa1, 0, 0, 0);
        }
#pragma unroll
        for (int r = 0; r < 4; ++r) {
            long row = (long)win * 144 + s * 16 + rb + r;
            attn_o[row * 384 + head * 32 + fr]      = f2bf(oa0[r] * sm[r]);
            attn_o[row * 384 + head * 32 + 16 + fr] = f2bf(oa1[r] * sm[r]);
        }
    }
}

// ---------------- LayerNorm + residual (wave per token) ----------------

template<bool MAP>  // MAP: tin rows are window-token order (proj path)
__global__ __launch_bounds__(256) void ln_res_k(
    const u16* __restrict__ tin, const float* __restrict__ res,
    const float* __restrict__ g, const float* __restrict__ bb,
    float* __restrict__ outp)
{
    const int token = blockIdx.x * 4 + (threadIdx.x >> 6);
    const int lane = threadIdx.x & 63;
    long srow;
    if constexpr (MAP) {
        int b = token / 2304, hw = token - b * 2304;
        int h = hw / 48, w = hw - h * 48;
        int sh = h + 42; if (sh >= 48) sh -= 48;   // (h - 6) mod 48
        int sw = w + 42; if (sw >= 48) sw -= 48;
        int wh = sh / 12, r = sh - wh * 12;
        int ww = sw / 12, cc = sw - ww * 12;
        srow = (long)(b * 16 + wh * 4 + ww) * 144 + r * 12 + cc;
    } else {
        srow = token;
    }
    const u16* src = tin + srow * 384;
    float v[6];
    {
        const ushort2* s2 = (const ushort2*)src;
#pragma unroll
        for (int i = 0; i < 3; ++i) {
            ushort2 p = s2[lane * 3 + i];
            v[i * 2] = bf2f(p.x); v[i * 2 + 1] = bf2f(p.y);
        }
    }
    float s1 = 0.f, s2 = 0.f;
#pragma unroll
    for (int i = 0; i < 6; ++i) { s1 += v[i]; s2 += v[i] * v[i]; }
#pragma unroll
    for (int o = 1; o < 64; o <<= 1) { s1 += __shfl_xor(s1, o); s2 += __shfl_xor(s2, o); }
    float mean = s1 * (1.f / 384.f);
    float var = s2 * (1.f / 384.f) - mean * mean;
    float rs = rsqrtf(var + 1e-5f);
    const float* rr = res + (long)token * 384;
    float* oo = outp + (long)token * 384;
#pragma unroll
    for (int i = 0; i < 6; ++i) {
        int c = lane * 6 + i;
        oo[c] = rr[c] + (v[i] - mean) * rs * g[c] + bb[c];
    }
}

// ---------------- launch ----------------

extern "C" void kernel_launch(void* const* d_in, const int* in_sizes, int n_in,
                              void* d_out, int out_size, void* d_ws, size_t ws_size,
                              hipStream_t stream) {
    (void)in_sizes; (void)n_in; (void)out_size; (void)ws_size;
    const float* x      = (const float*)d_in[0];
    const float* table  = (const float*)d_in[1];
    const int*   rpi    = (const int*)d_in[2];
    const float* mask   = (const float*)d_in[3];
    const float* qkv_w  = (const float*)d_in[4];
    const float* q_bias = (const float*)d_in[5];
    const float* v_bias = (const float*)d_in[6];
    const float* lsc    = (const float*)d_in[7];
    const float* cpb_w1 = (const float*)d_in[8];
    const float* cpb_b1 = (const float*)d_in[9];
    const float* cpb_w2 = (const float*)d_in[10];
    const float* proj_w = (const float*)d_in[11];
    const float* proj_b = (const float*)d_in[12];
    const float* n1g    = (const float*)d_in[13];
    const float* n1b    = (const float*)d_in[14];
    const float* n2g    = (const float*)d_in[15];
    const float* n2b    = (const float*)d_in[16];
    const float* fc1_w  = (const float*)d_in[17];
    const float* fc1_b  = (const float*)d_in[18];
    const float* fc2_w  = (const float*)d_in[19];
    const float* fc2_b  = (const float*)d_in[20];
    float* outp = (float*)d_out;

    char* ws = (char*)d_ws;
    const size_t offA    = 0;                       // qkv -> proj_out -> h
    const size_t offB    = 226492416;               // attn_out -> t2
    const size_t offY    = offB + 56623104;         // y1 fp32
    const size_t offBias = offY + 113246208;        // bias16
    const size_t offTab  = offBias + 995328;
    const size_t offQW   = offTab + 25600;
    const size_t offPW   = offQW + 884736;
    const size_t offF1   = offPW + 294912;
    const size_t offF2   = offF1 + 1179648;
    const size_t offQB   = offF2 + 1179648;

    u16*   qkvb    = (u16*)(ws + offA);
    u16*   proj_o  = (u16*)(ws + offA);
    u16*   hbuf    = (u16*)(ws + offA);
    u16*   attn_o  = (u16*)(ws + offB);
    u16*   t2      = (u16*)(ws + offB);
    float* y1      = (float*)(ws + offY);
    float* bias16  = (float*)(ws + offBias);
    float* tab     = (float*)(ws + offTab);
    u16*   qkv_wT  = (u16*)(ws + offQW);
    u16*   proj_wT = (u16*)(ws + offPW);
    u16*   fc1_wT  = (u16*)(ws + offF1);
    u16*   fc2_wT  = (u16*)(ws + offF2);
    float* qkvbias = (float*)(ws + offQB);

    wt_convert<<<(384 * 1152 + 255) / 256, 256, 0, stream>>>(qkv_w, qkv_wT, 384, 1152);
    wt_convert<<<(384 * 384 + 255) / 256, 256, 0, stream>>>(proj_w, proj_wT, 384, 384);
    wt_convert<<<(384 * 1536 + 255) / 256, 256, 0, stream>>>(fc1_w, fc1_wT, 384, 1536);
    wt_convert<<<(1536 * 384 + 255) / 256, 256, 0, stream>>>(fc2_w, fc2_wT, 1536, 384);
    build_qkv_bias<<<5, 256, 0, stream>>>(q_bias, v_bias, qkvbias);
    cpb_tab<<<529, 256, 0, stream>>>(table, cpb_w1, cpb_b1, cpb_w2, tab);
    cpb_bias<<<(12 * 144 * 144 + 255) / 256, 256, 0, stream>>>(tab, rpi, bias16);

    // qkv = gather(shift+window)(x) @ qkv_w + bias  -> [win][3][head][144][32] bf16
    gemm_k<true, true, EPI_QKV><<<dim3(576, 9), 256, 0, stream>>>(
        (const void*)x, qkv_wT, qkvbias, qkvb, 1152, 384);

    attn_k<<<6144, 192, 0, stream>>>(qkvb, bias16, mask, lsc, attn_o);

    // proj
    gemm_k<false, false, EPI_PLAIN><<<dim3(576, 3), 256, 0, stream>>>(
        (const void*)attn_o, proj_wT, proj_b, proj_o, 384, 384);

    // y1 = x + LN1(window_reverse(proj))
    ln_res_k<true><<<18432, 256, 0, stream>>>(proj_o, x, n1g, n1b, y1);

    // h = gelu(y1 @ fc1 + b)
    gemm_k<true, false, EPI_GELU><<<dim3(576, 12), 256, 0, stream>>>(
        (const void*)y1, fc1_wT, fc1_b, hbuf, 1536, 384);

    // t2 = h @ fc2 + b
    gemm_k<false, false, EPI_PLAIN><<<dim3(576, 3), 256, 0, stream>>>(
        (const void*)hbuf, fc2_wT, fc2_b, t2, 384, 1536);

    // out = y1 + LN2(t2)
    ln_res_k<false><<<18432, 256, 0, stream>>>(t2, y1, n2g, n2b, outp);
}

// Round 2
// 815.076 us; speedup vs baseline: 1.1644x; 1.1644x over previous
//
#include <hip/hip_runtime.h>

// SwinV2 block, MI355X. All GEMMs: bf16 MFMA 16x16x32, fp32 accum,
// global_load_lds(16B) staging, BK=32 double-buffered, producer-side
// XOR swizzle (col ^ ((row&3)<<3) within 32-elem K-blocks), XCD-chunked
// N-fast grid.

typedef unsigned int uint32;
typedef unsigned short u16;
typedef __attribute__((ext_vector_type(4))) float f32x4;
typedef __attribute__((ext_vector_type(8))) __bf16 bf16x8;

static __device__ __forceinline__ u16 f2bf(float f) {
    union { float f; uint32 u; } v; v.f = f;
    uint32 r = v.u + 0x7fffu + ((v.u >> 16) & 1u);
    return (u16)(r >> 16);
}
static __device__ __forceinline__ float bf2f(u16 h) {
    union { uint32 u; float f; } v; v.u = ((uint32)h) << 16; return v.f;
}
static __device__ __forceinline__ uint32 pack2(float a, float b) {
    return (uint32)f2bf(a) | ((uint32)f2bf(b) << 16);
}
static __device__ __forceinline__ float blo(uint32 u){ union{uint32 u;float f;}v; v.u=u<<16; return v.f; }
static __device__ __forceinline__ float bhi(uint32 u){ union{uint32 u;float f;}v; v.u=u&0xffff0000u; return v.f; }

// async global->LDS, 16B per lane; LDS dest must be wave-uniform base
typedef __attribute__((address_space(1))) const void gas_void;
typedef __attribute__((address_space(3))) void las_void;
static __device__ __forceinline__ void glds16(const void* g, void* l) {
    __builtin_amdgcn_global_load_lds((gas_void*)g, (las_void*)l, 16, 0, 0);
}

#define SWZ(c, row) ((c) ^ (((row) & 3) << 3))

// ---------------- setup kernels ----------------

// WT[n][swz(k,n)] = bf16(W[k][n]); W is (K,N) row-major fp32
__global__ void wt_convert(const float* __restrict__ W, u16* __restrict__ WT, int K, int N) {
    long idx = (long)blockIdx.x * 256 + threadIdx.x;
    long tot = (long)K * N;
    if (idx >= tot) return;
    int n = (int)(idx / K), k = (int)(idx - (long)n * K);
    WT[(long)n * K + SWZ(k, n)] = f2bf(W[(long)k * N + n]);
}

__global__ void build_qkv_bias(const float* __restrict__ qb, const float* __restrict__ vb,
                               float* __restrict__ outb) {
    int c = blockIdx.x * 256 + threadIdx.x;
    if (c >= 1152) return;
    outb[c] = (c < 384) ? qb[c] : ((c < 768) ? 0.f : vb[c - 768]);
}

__global__ void cpb_tab(const float* __restrict__ table, const float* __restrict__ w1,
                        const float* __restrict__ b1, const float* __restrict__ w2,
                        float* __restrict__ tab) {
    __shared__ float hid[512];
    int e = blockIdx.x;
    float tx = table[e * 2 + 0], ty = table[e * 2 + 1];
    for (int u = threadIdx.x; u < 512; u += 256)
        hid[u] = fmaxf(tx * w1[u] + ty * w1[512 + u] + b1[u], 0.f);
    __syncthreads();
    if (threadIdx.x < 12) {
        float s = 0.f;
        for (int u = 0; u < 512; ++u) s += hid[u] * w2[u * 12 + threadIdx.x];
        tab[e * 12 + threadIdx.x] = s;
    }
}

__global__ void cpb_bias(const float* __restrict__ tab, const int* __restrict__ rpi,
                         float* __restrict__ bias16) {
    int idx = blockIdx.x * 256 + threadIdx.x;
    if (idx >= 12 * 144 * 144) return;
    int h = idx / 20736, ij = idx - h * 20736;
    float t = tab[rpi[ij] * 12 + h];
    bias16[idx] = 16.f / (1.f + __expf(-t));
}

// x (fp32, pixel rows) -> xw (bf16, window-token rows, swizzled)
__global__ void gather_xbf(const float* __restrict__ x, u16* __restrict__ xw) {
    int idx = blockIdx.x * 256 + threadIdx.x;   // 73728*48 threads, 8 elems each
    if (idx >= 73728 * 48) return;
    int row = idx / 48, c = (idx - row * 48) * 8;
    int win = row / 144, n = row - win * 144;
    int b = win >> 4, wi = win & 15;
    int r = n / 12, cc = n - r * 12;
    int sh = ((wi >> 2) * 12 + r + 6) % 48;
    int sw = ((wi & 3) * 12 + cc + 6) % 48;
    long src = ((long)(b * 2304 + sh * 48 + sw)) * 384 + c;
    float4 f0 = *(const float4*)(x + src);
    float4 f1 = *(const float4*)(x + src + 4);
    uint4 o;
    o.x = pack2(f0.x, f0.y); o.y = pack2(f0.z, f0.w);
    o.z = pack2(f1.x, f1.y); o.w = pack2(f1.z, f1.w);
    *(uint4*)(xw + (long)row * 384 + SWZ(c, row)) = o;
}

// ---------------- GEMM: 128x128 tile, BK=32, 4 waves, glds staging ----------------

enum { EPI_QKV = 0, EPI_PLAIN = 1, EPI_GELU = 2 };

template<int EPI, bool OSWZ>
__global__ __launch_bounds__(256) void gemm_k(
    const u16* __restrict__ Ag, const u16* __restrict__ Bg,
    const float* __restrict__ bias, u16* __restrict__ outp,
    int N, int K, int ntn)
{
    __shared__ __align__(16) u16 As[2][128 * 32];
    __shared__ __align__(16) u16 Bs[2][128 * 32];
    const int tid = threadIdx.x, lane = tid & 63, wid = tid >> 6;
    // XCD-chunked, n-fast block order (gridDim.x % 8 == 0 for all launches)
    const int qq = gridDim.x >> 3;
    const int wg = (blockIdx.x & 7) * qq + (blockIdx.x >> 3);
    const int mIdx = wg / ntn, nIdx = wg - mIdx * ntn;
    const int m0 = mIdx << 7, n0 = nIdx << 7;

    const int wrow = (wid >> 1) << 6, wcol = (wid & 1) << 6;
    const int fr = lane & 15, gsel = lane >> 4;

    // staging geometry: one glds16 = 64 lanes x 16B = 16 rows x 32 elems
    const int s_r = (wid << 5) + (lane >> 2);   // + q*16
    const int s_g = (lane & 3) << 3;
    const long a_base = (long)(m0 + s_r) * K + s_g;
    const long b_base = (long)(n0 + s_r) * K + s_g;
    const long qstep = (long)16 * K;

    auto stage = [&](int buf, int kt) {
        const int k0 = kt << 5;
#pragma unroll
        for (int q = 0; q < 2; ++q) {
            glds16(Ag + a_base + qstep * q + k0, &As[buf][(wid * 32 + q * 16) * 32]);
            glds16(Bg + b_base + qstep * q + k0, &Bs[buf][(wid * 32 + q * 16) * 32]);
        }
    };

    int arow[4], acol[4], brow[4], bcol[4];
#pragma unroll
    for (int i = 0; i < 4; ++i) {
        arow[i] = wrow + i * 16 + fr; acol[i] = SWZ(gsel * 8, arow[i]);
        brow[i] = wcol + i * 16 + fr; bcol[i] = SWZ(gsel * 8, brow[i]);
    }

    f32x4 acc[4][4];
    const f32x4 zero4 = {0.f, 0.f, 0.f, 0.f};
#pragma unroll
    for (int i = 0; i < 4; ++i)
#pragma unroll
        for (int j = 0; j < 4; ++j) acc[i][j] = zero4;

    const int nk = K >> 5;
    stage(0, 0);
    int cur = 0;
    for (int kt = 0; kt < nk; ++kt) {
        __syncthreads();                       // drains glds of buf[cur]
        if (kt + 1 < nk) stage(cur ^ 1, kt + 1);
        bf16x8 af[4], bg[4];
#pragma unroll
        for (int i = 0; i < 4; ++i) af[i] = *(const bf16x8*)&As[cur][arow[i] * 32 + acol[i]];
#pragma unroll
        for (int j = 0; j < 4; ++j) bg[j] = *(const bf16x8*)&Bs[cur][brow[j] * 32 + bcol[j]];
#pragma unroll
        for (int i = 0; i < 4; ++i)
#pragma unroll
            for (int j = 0; j < 4; ++j)
                acc[i][j] = __builtin_amdgcn_mfma_f32_16x16x32_bf16(af[i], bg[j], acc[i][j], 0, 0, 0);
        cur ^= 1;
    }

    const int rbase = (lane >> 4) << 2;
#pragma unroll
    for (int i = 0; i < 4; ++i) {
#pragma unroll
        for (int j = 0; j < 4; ++j) {
            const int gn = n0 + wcol + j * 16 + fr;
            const float bv = bias[gn];
#pragma unroll
            for (int r = 0; r < 4; ++r) {
                const int gm = m0 + wrow + i * 16 + rbase + r;
                float v = acc[i][j][r] + bv;
                if constexpr (EPI == EPI_GELU)
                    v = 0.5f * v * (1.f + erff(v * 0.70710678118654752f));
                if constexpr (EPI == EPI_QKV) {
                    int win = gm / 144, n = gm - win * 144;
                    int which = gn / 384, c = gn - which * 384;
                    int head = c >> 5, d = c & 31;
                    outp[(((long)win * 3 + which) * 12 + head) * 4608 + n * 32 + d] = f2bf(v);
                } else {
                    long oc = OSWZ ? SWZ(gn, gm) : gn;
                    outp[(long)gm * N + oc] = f2bf(v);
                }
            }
        }
    }
}

// ---------------- attention: one (window, head) per block, 3 waves ----------------

__global__ __launch_bounds__(192) void attn_k(
    const u16* __restrict__ qkv,      // [512][3][12][144][32] bf16
    const float* __restrict__ bias16, // [12][144][144]
    const float* __restrict__ mask,   // [16][144][144]
    const float* __restrict__ lsc,    // [12]
    u16* __restrict__ attn_o)         // [512 tok rows][384] bf16, swizzled cols
{
    __shared__ __align__(16) u16 KL[144][40];
    __shared__ __align__(16) u16 VT[32][168];
    __shared__ __align__(16) u16 PL[3][16][168];
    const int blk = blockIdx.x;
    const int win = blk / 12, head = blk - win * 12;
    const int tid = threadIdx.x, lane = tid & 63, wid = tid >> 6;
    const long base = ((long)win * 36 + head) * 4608;
    const u16* Qp = qkv + base;
    const u16* Kp = qkv + base + 12 * 4608;
    const u16* Vp = qkv + base + 24 * 4608;
    const float scale = __expf(fminf(lsc[head], 4.6051701859880914f));

    if (tid < 144) {
        const uint4* s = (const uint4*)(Kp + tid * 32);
        uint4 uu[4] = { s[0], s[1], s[2], s[3] };
        float f[32];
#pragma unroll
        for (int q = 0; q < 4; ++q) {
            f[q*8+0]=blo(uu[q].x); f[q*8+1]=bhi(uu[q].x);
            f[q*8+2]=blo(uu[q].y); f[q*8+3]=bhi(uu[q].y);
            f[q*8+4]=blo(uu[q].z); f[q*8+5]=bhi(uu[q].z);
            f[q*8+6]=blo(uu[q].w); f[q*8+7]=bhi(uu[q].w);
        }
        float ss = 0.f;
#pragma unroll
        for (int i = 0; i < 32; ++i) ss += f[i] * f[i];
        float inv = 1.f / fmaxf(sqrtf(ss), 1e-12f);
        uint32 pk[16];
#pragma unroll
        for (int i = 0; i < 16; ++i) pk[i] = pack2(f[2*i] * inv, f[2*i+1] * inv);
        uint4* d = (uint4*)&KL[tid][0];
        d[0] = make_uint4(pk[0], pk[1], pk[2], pk[3]);
        d[1] = make_uint4(pk[4], pk[5], pk[6], pk[7]);
        d[2] = make_uint4(pk[8], pk[9], pk[10], pk[11]);
        d[3] = make_uint4(pk[12], pk[13], pk[14], pk[15]);
        const uint4* sv = (const uint4*)(Vp + tid * 32);
        uint4 vv[4] = { sv[0], sv[1], sv[2], sv[3] };
        u16 vs[32];
#pragma unroll
        for (int q = 0; q < 4; ++q) {
            vs[q*8+0] = (u16)(vv[q].x & 0xffffu); vs[q*8+1] = (u16)(vv[q].x >> 16);
            vs[q*8+2] = (u16)(vv[q].y & 0xffffu); vs[q*8+3] = (u16)(vv[q].y >> 16);
            vs[q*8+4] = (u16)(vv[q].z & 0xffffu); vs[q*8+5] = (u16)(vv[q].z >> 16);
            vs[q*8+6] = (u16)(vv[q].w & 0xffffu); vs[q*8+7] = (u16)(vv[q].w >> 16);
        }
#pragma unroll
        for (int d2 = 0; d2 < 32; ++d2) VT[d2][tid] = vs[d2];
    }
    for (int idx = tid; idx < 512; idx += 192) VT[idx >> 4][144 + (idx & 15)] = 0;
    __syncthreads();

    const int fr = lane & 15, fk = (lane >> 4) << 3, rb = (lane >> 4) << 2;
    const int wim = win & 15;
    const f32x4 zero4 = {0.f, 0.f, 0.f, 0.f};

    for (int s = wid; s < 9; s += 3) {
        const uint4 qu = *(const uint4*)(Qp + (s * 16 + fr) * 32 + fk);
        float qf[8];
        qf[0]=blo(qu.x); qf[1]=bhi(qu.x); qf[2]=blo(qu.y); qf[3]=bhi(qu.y);
        qf[4]=blo(qu.z); qf[5]=bhi(qu.z); qf[6]=blo(qu.w); qf[7]=bhi(qu.w);
        float ss = 0.f;
#pragma unroll
        for (int i = 0; i < 8; ++i) ss += qf[i] * qf[i];
        ss += __shfl_xor(ss, 16);
        ss += __shfl_xor(ss, 32);
        float qinv = scale / fmaxf(sqrtf(ss), 1e-12f);
        union { uint32 u[4]; bf16x8 v; } cv;
#pragma unroll
        for (int i = 0; i < 4; ++i) cv.u[i] = pack2(qf[2*i] * qinv, qf[2*i+1] * qinv);
        bf16x8 aq = cv.v;

        f32x4 sacc[9];
#pragma unroll
        for (int jt = 0; jt < 9; ++jt) sacc[jt] = zero4;
#pragma unroll
        for (int jt = 0; jt < 9; ++jt) {
            bf16x8 bk = *(const bf16x8*)&KL[jt * 16 + fr][fk];
            sacc[jt] = __builtin_amdgcn_mfma_f32_16x16x32_bf16(aq, bk, sacc[jt], 0, 0, 0);
        }
        float mx[4] = {-1e30f, -1e30f, -1e30f, -1e30f};
#pragma unroll
        for (int jt = 0; jt < 9; ++jt) {
            int gj = jt * 16 + fr;
#pragma unroll
            for (int r = 0; r < 4; ++r) {
                int gi = s * 16 + rb + r;
                float v = sacc[jt][r] + bias16[(head * 144 + gi) * 144 + gj]
                                      + mask[(wim * 144 + gi) * 144 + gj];
                sacc[jt][r] = v;
                mx[r] = fmaxf(mx[r], v);
            }
        }
#pragma unroll
        for (int r = 0; r < 4; ++r) {
#pragma unroll
            for (int o = 1; o < 16; o <<= 1) mx[r] = fmaxf(mx[r], __shfl_xor(mx[r], o));
        }
        float sm[4] = {0.f, 0.f, 0.f, 0.f};
#pragma unroll
        for (int jt = 0; jt < 9; ++jt)
#pragma unroll
            for (int r = 0; r < 4; ++r) {
                float e = __expf(sacc[jt][r] - mx[r]);
                sacc[jt][r] = e;
                sm[r] += e;
            }
#pragma unroll
        for (int r = 0; r < 4; ++r) {
#pragma unroll
            for (int o = 1; o < 16; o <<= 1) sm[r] += __shfl_xor(sm[r], o);
            sm[r] = 1.f / sm[r];
        }
#pragma unroll
        for (int jt = 0; jt < 9; ++jt)
#pragma unroll
            for (int r = 0; r < 4; ++r)
                PL[wid][rb + r][jt * 16 + fr] = f2bf(sacc[jt][r]);
#pragma unroll
        for (int r = 0; r < 4; ++r) PL[wid][rb + r][144 + fr] = 0;

        f32x4 oa0 = zero4, oa1 = zero4;
#pragma unroll
        for (int kt = 0; kt < 5; ++kt) {
            bf16x8 ap  = *(const bf16x8*)&PL[wid][fr][kt * 32 + fk];
            bf16x8 bv0 = *(const bf16x8*)&VT[fr][kt * 32 + fk];
            bf16x8 bv1 = *(const bf16x8*)&VT[16 + fr][kt * 32 + fk];
            oa0 = __builtin_amdgcn_mfma_f32_16x16x32_bf16(ap, bv0, oa0, 0, 0, 0);
            oa1 = __builtin_amdgcn_mfma_f32_16x16x32_bf16(ap, bv1, oa1, 0, 0, 0);
        }
#pragma unroll
        for (int r = 0; r < 4; ++r) {
            long row = (long)win * 144 + s * 16 + rb + r;
            int c0 = head * 32 + fr, c1 = head * 32 + 16 + fr;
            attn_o[row * 384 + SWZ(c0, row)] = f2bf(oa0[r] * sm[r]);
            attn_o[row * 384 + SWZ(c1, row)] = f2bf(oa1[r] * sm[r]);
        }
    }
}

// ---------------- LayerNorm + residual ----------------

// y1b[token][swz] = bf16( x[token] + LN(proj_o[map(token)])*g + b )
__global__ __launch_bounds__(256) void ln1_k(
    const u16* __restrict__ pin, const float* __restrict__ x,
    const float* __restrict__ g, const float* __restrict__ bb,
    u16* __restrict__ y1b)
{
    const int token = blockIdx.x * 4 + (threadIdx.x >> 6);
    const int lane = threadIdx.x & 63;
    int b = token / 2304, hw = token - b * 2304;
    int h = hw / 48, w = hw - h * 48;
    int sh = h + 42; if (sh >= 48) sh -= 48;
    int sw = w + 42; if (sw >= 48) sw -= 48;
    int wh = sh / 12, r = sh - wh * 12;
    int ww = sw / 12, cc = sw - ww * 12;
    long srow = (long)(b * 16 + wh * 4 + ww) * 144 + r * 12 + cc;
    const u16* src = pin + srow * 384;
    float v[6];
    {
        const ushort2* s2 = (const ushort2*)src;
#pragma unroll
        for (int i = 0; i < 3; ++i) {
            ushort2 p = s2[lane * 3 + i];
            v[i * 2] = bf2f(p.x); v[i * 2 + 1] = bf2f(p.y);
        }
    }
    float s1 = 0.f, s2 = 0.f;
#pragma unroll
    for (int i = 0; i < 6; ++i) { s1 += v[i]; s2 += v[i] * v[i]; }
#pragma unroll
    for (int o = 1; o < 64; o <<= 1) { s1 += __shfl_xor(s1, o); s2 += __shfl_xor(s2, o); }
    float mean = s1 * (1.f / 384.f);
    float var = s2 * (1.f / 384.f) - mean * mean;
    float rs = rsqrtf(var + 1e-5f);
    const float* rr = x + (long)token * 384;
    u16* oo = y1b + (long)token * 384;
#pragma unroll
    for (int i = 0; i < 6; ++i) {
        int c = lane * 6 + i;
        oo[SWZ(c, token)] = f2bf(rr[c] + (v[i] - mean) * rs * g[c] + bb[c]);
    }
}

// out[token] = y1b[token] + LN(t2[token])*g + b   (fp32 out)
__global__ __launch_bounds__(256) void ln2_k(
    const u16* __restrict__ t2, const u16* __restrict__ y1b,
    const float* __restrict__ g, const float* __restrict__ bb,
    float* __restrict__ outp)
{
    const int token = blockIdx.x * 4 + (threadIdx.x >> 6);
    const int lane = threadIdx.x & 63;
    const u16* src = t2 + (long)token * 384;
    float v[6];
    {
        const ushort2* s2 = (const ushort2*)src;
#pragma unroll
        for (int i = 0; i < 3; ++i) {
            ushort2 p = s2[lane * 3 + i];
            v[i * 2] = bf2f(p.x); v[i * 2 + 1] = bf2f(p.y);
        }
    }
    float s1 = 0.f, s2 = 0.f;
#pragma unroll
    for (int i = 0; i < 6; ++i) { s1 += v[i]; s2 += v[i] * v[i]; }
#pragma unroll
    for (int o = 1; o < 64; o <<= 1) { s1 += __shfl_xor(s1, o); s2 += __shfl_xor(s2, o); }
    float mean = s1 * (1.f / 384.f);
    float var = s2 * (1.f / 384.f) - mean * mean;
    float rs = rsqrtf(var + 1e-5f);
    const u16* rr = y1b + (long)token * 384;
    float* oo = outp + (long)token * 384;
#pragma unroll
    for (int i = 0; i < 6; ++i) {
        int c = lane * 6 + i;
        oo[c] = bf2f(rr[SWZ(c, token)]) + (v[i] - mean) * rs * g[c] + bb[c];
    }
}

// ---------------- launch ----------------

extern "C" void kernel_launch(void* const* d_in, const int* in_sizes, int n_in,
                              void* d_out, int out_size, void* d_ws, size_t ws_size,
                              hipStream_t stream) {
    (void)in_sizes; (void)n_in; (void)out_size; (void)ws_size;
    const float* x      = (const float*)d_in[0];
    const float* table  = (const float*)d_in[1];
    const int*   rpi    = (const int*)d_in[2];
    const float* mask   = (const float*)d_in[3];
    const float* qkv_w  = (const float*)d_in[4];
    const float* q_bias = (const float*)d_in[5];
    const float* v_bias = (const float*)d_in[6];
    const float* lsc    = (const float*)d_in[7];
    const float* cpb_w1 = (const float*)d_in[8];
    const float* cpb_b1 = (const float*)d_in[9];
    const float* cpb_w2 = (const float*)d_in[10];
    const float* proj_w = (const float*)d_in[11];
    const float* proj_b = (const float*)d_in[12];
    const float* n1g    = (const float*)d_in[13];
    const float* n1b    = (const float*)d_in[14];
    const float* n2g    = (const float*)d_in[15];
    const float* n2b    = (const float*)d_in[16];
    const float* fc1_w  = (const float*)d_in[17];
    const float* fc1_b  = (const float*)d_in[18];
    const float* fc2_w  = (const float*)d_in[19];
    const float* fc2_b  = (const float*)d_in[20];
    float* outp = (float*)d_out;

    char* ws = (char*)d_ws;
    // region A: qkvb (170MB) -> proj_o (56.6MB) -> h (226.5MB)
    const size_t offA    = 0;
    // region B: attn_o -> t2 (56.6MB)
    const size_t offB    = 226492416;
    // region C: xw (gathered bf16 x) -> y1b (56.6MB)
    const size_t offC    = offB + 56623104;
    const size_t offBias = offC + 56623104;
    const size_t offTab  = offBias + 995328;
    const size_t offQW   = offTab + 25600;
    const size_t offPW   = offQW + 884736;
    const size_t offF1   = offPW + 294912;
    const size_t offF2   = offF1 + 1179648;
    const size_t offQB   = offF2 + 1179648;

    u16*   qkvb    = (u16*)(ws + offA);
    u16*   proj_o  = (u16*)(ws + offA);
    u16*   hbuf    = (u16*)(ws + offA);
    u16*   attn_o  = (u16*)(ws + offB);
    u16*   t2      = (u16*)(ws + offB);
    u16*   xw      = (u16*)(ws + offC);
    u16*   y1b     = (u16*)(ws + offC);
    float* bias16  = (float*)(ws + offBias);
    float* tab     = (float*)(ws + offTab);
    u16*   qkv_wT  = (u16*)(ws + offQW);
    u16*   proj_wT = (u16*)(ws + offPW);
    u16*   fc1_wT  = (u16*)(ws + offF1);
    u16*   fc2_wT  = (u16*)(ws + offF2);
    float* qkvbias = (float*)(ws + offQB);

    wt_convert<<<(384 * 1152 + 255) / 256, 256, 0, stream>>>(qkv_w, qkv_wT, 384, 1152);
    wt_convert<<<(384 * 384 + 255) / 256, 256, 0, stream>>>(proj_w, proj_wT, 384, 384);
    wt_convert<<<(384 * 1536 + 255) / 256, 256, 0, stream>>>(fc1_w, fc1_wT, 384, 1536);
    wt_convert<<<(1536 * 384 + 255) / 256, 256, 0, stream>>>(fc2_w, fc2_wT, 1536, 384);
    build_qkv_bias<<<5, 256, 0, stream>>>(q_bias, v_bias, qkvbias);
    cpb_tab<<<529, 256, 0, stream>>>(table, cpb_w1, cpb_b1, cpb_w2, tab);
    cpb_bias<<<(12 * 144 * 144 + 255) / 256, 256, 0, stream>>>(tab, rpi, bias16);
    gather_xbf<<<(73728 * 48 + 255) / 256, 256, 0, stream>>>(x, xw);

    // qkv = xw @ qkv_w + bias -> [win][3][head][144][32] bf16 (plain)
    gemm_k<EPI_QKV, false><<<576 * 9, 256, 0, stream>>>(xw, qkv_wT, qkvbias, qkvb, 1152, 384, 9);

    attn_k<<<6144, 192, 0, stream>>>(qkvb, bias16, mask, lsc, attn_o);

    // proj: attn_o @ proj_w + b -> proj_o (plain, window rows)
    gemm_k<EPI_PLAIN, false><<<576 * 3, 256, 0, stream>>>(attn_o, proj_wT, proj_b, proj_o, 384, 384, 3);

    // y1b = bf16(x + LN1(window_reverse(proj_o)))  (swizzled)
    ln1_k<<<18432, 256, 0, stream>>>(proj_o, x, n1g, n1b, y1b);

    // h = gelu(y1b @ fc1 + b)  (swizzled out)
    gemm_k<EPI_GELU, true><<<576 * 12, 256, 0, stream>>>(y1b, fc1_wT, fc1_b, hbuf, 1536, 384, 12);

    // t2 = h @ fc2 + b  (plain)
    gemm_k<EPI_PLAIN, false><<<576 * 3, 256, 0, stream>>>(hbuf, fc2_wT, fc2_b, t2, 384, 1536, 3);

    // out = y1b + LN2(t2)
    ln2_k<<<18432, 256, 0, stream>>>(t2, y1b, n2g, n2b, outp);
}